// Round 7
// baseline (557.677 us; speedup 1.0000x reference)
//
#include <hip/hip_runtime.h>
#include <math.h>

#define T_DATA 10000
#define E_NO 2000
#define I_NO 500
#define SUB_NO 64
#define KERN_LEN 201
#define PAD 100
#define NBLK 314              // packed words region (314*32 = 10048 steps)
typedef unsigned long long ull;

// ---------------- K0: extract one-hot assignments ----------------
__global__ void assign_kernel(const float* __restrict__ Ce, const float* __restrict__ Ci,
                              int* __restrict__ ae, int* __restrict__ ai) {
    int idx = blockIdx.x * 256 + threadIdx.x;
    if (idx < E_NO) {
        int a = 0;
        for (int s = 0; s < SUB_NO; ++s)
            if (Ce[(size_t)s * E_NO + idx] != 0.0f) a = s;
        ae[idx] = a;
    } else if (idx < E_NO + I_NO) {
        int i = idx - E_NO;
        int a = 0;
        for (int s = 0; s < SUB_NO; ++s)
            if (Ci[(size_t)s * I_NO + i] != 0.0f) a = s;
        ai[i] = a;
    }
}

// ---------------- K1: drive[t][s] = cnt_e*we[s] + cnt_i*wi[s] ----------------
__global__ void drive_kernel(const float* __restrict__ Se, const float* __restrict__ Si,
                             const float* __restrict__ wraw,
                             const int* __restrict__ ae, const int* __restrict__ ai,
                             float* __restrict__ drive) {
    __shared__ float be[SUB_NO];
    __shared__ float bi[SUB_NO];
    int t = blockIdx.x;
    int tid = threadIdx.x;
    if (tid < SUB_NO) { be[tid] = 0.0f; bi[tid] = 0.0f; }
    __syncthreads();
    const float4* se4 = (const float4*)(Se + (size_t)t * E_NO);
    for (int e4 = tid; e4 < E_NO / 4; e4 += 256) {
        float4 v = se4[e4];
        int b = e4 * 4;
        if (v.x != 0.0f) atomicAdd(&be[ae[b + 0]], 1.0f);
        if (v.y != 0.0f) atomicAdd(&be[ae[b + 1]], 1.0f);
        if (v.z != 0.0f) atomicAdd(&be[ae[b + 2]], 1.0f);
        if (v.w != 0.0f) atomicAdd(&be[ae[b + 3]], 1.0f);
    }
    const float4* si4 = (const float4*)(Si + (size_t)t * I_NO);
    for (int i4 = tid; i4 < I_NO / 4; i4 += 256) {
        float4 v = si4[i4];
        int b = i4 * 4;
        if (v.x != 0.0f) atomicAdd(&bi[ai[b + 0]], 1.0f);
        if (v.y != 0.0f) atomicAdd(&bi[ai[b + 1]], 1.0f);
        if (v.z != 0.0f) atomicAdd(&bi[ai[b + 2]], 1.0f);
        if (v.w != 0.0f) atomicAdd(&bi[ai[b + 3]], 1.0f);
    }
    __syncthreads();
    if (tid < SUB_NO) {
        float we = (float)exp((double)wraw[2 * tid]);
        float wi = -(float)exp((double)wraw[2 * tid + 1]);
        drive[(size_t)t * SUB_NO + tid] =
            __fadd_rn(__fmul_rn(be[tid], we), __fmul_rn(bi[tid], wi));
    }
}

// ================= HOT ENGINES: whole scan in one asm loop =================
// Identical to R6 (validated bit-exact). Launched on 256 blocks: every block
// computes the same scan and stores identical values to identical addresses
// (benign duplicate writes) — occupying all CUs keeps DVFS at high SCLK.

#define SL(B,NB,OFF,LIT,BITS) \
  "v_and_b32 v16, vcc_lo, %[rlo]\n\t" \
  "v_and_b32 v17, vcc_hi, %[rhi]\n\t" \
  "v_cndmask_b32 v21, v29, " B ", vcc\n\t" \
  "v_bcnt_u32_b32 v18, v16, 0\n\t" \
  "v_bcnt_u32_b32 v18, v17, v18\n\t" \
  "v_cvt_f32_u32 v19, v18\n\t" \
  "global_load_dword " B ", v[24:25], off offset:" OFF "\n\t" \
  "v_mul_f32 v20, v19, %[p]\n\t" \
  "v_add_f32 v28, v21, v20\n\t" \
  "v_cmp_gt_f32 vcc, v28, %[thr]\n\t" \
  "v_mul_f32 v29, v28, %[dec]\n\t" \
  "v_or_b32 v22, " LIT ", " BITS "\n\t" \
  "v_cndmask_b32 " BITS ", " BITS ", v22, vcc\n\t" \
  "s_waitcnt vmcnt(31)\n\t" \
  "v_add_f32 v29, v29, " NB "\n\t"

#define SL0(B,NB,OFF,BITS) \
  "v_and_b32 v16, vcc_lo, %[rlo]\n\t" \
  "v_and_b32 v17, vcc_hi, %[rhi]\n\t" \
  "v_cndmask_b32 v21, v29, " B ", vcc\n\t" \
  "v_bcnt_u32_b32 v18, v16, 0\n\t" \
  "v_bcnt_u32_b32 v18, v17, v18\n\t" \
  "v_cvt_f32_u32 v19, v18\n\t" \
  "global_load_dword " B ", v[24:25], off offset:" OFF "\n\t" \
  "v_mul_f32 v20, v19, %[p]\n\t" \
  "v_add_f32 v28, v21, v20\n\t" \
  "v_cmp_gt_f32 vcc, v28, %[thr]\n\t" \
  "v_mul_f32 v29, v28, %[dec]\n\t" \
  "v_cndmask_b32 " BITS ", 0, 1, vcc\n\t" \
  "s_waitcnt vmcnt(31)\n\t" \
  "v_add_f32 v29, v29, " NB "\n\t"

#define SB(B,NB,OFF,LIT,BITS) \
  "v_and_b32 v16, vcc_lo, %[rlo]\n\t" \
  "v_and_b32 v17, vcc_hi, %[rhi]\n\t" \
  "v_cndmask_b32 v21, v29, " B ", vcc\n\t" \
  "v_bcnt_u32_b32 v18, v16, 0\n\t" \
  "v_bcnt_u32_b32 v18, v17, v18\n\t" \
  "v_lshlrev_b32 v18, 2, v18\n\t" \
  "ds_bpermute_b32 v20, v18, %[vt]\n\t" \
  "global_load_dword " B ", v[24:25], off offset:" OFF "\n\t" \
  "s_waitcnt lgkmcnt(0)\n\t" \
  "v_add_f32 v28, v21, v20\n\t" \
  "v_cmp_gt_f32 vcc, v28, %[thr]\n\t" \
  "v_mul_f32 v29, v28, %[dec]\n\t" \
  "v_or_b32 v22, " LIT ", " BITS "\n\t" \
  "v_cndmask_b32 " BITS ", " BITS ", v22, vcc\n\t" \
  "s_waitcnt vmcnt(31)\n\t" \
  "v_add_f32 v29, v29, " NB "\n\t"

#define SB0(B,NB,OFF,BITS) \
  "v_and_b32 v16, vcc_lo, %[rlo]\n\t" \
  "v_and_b32 v17, vcc_hi, %[rhi]\n\t" \
  "v_cndmask_b32 v21, v29, " B ", vcc\n\t" \
  "v_bcnt_u32_b32 v18, v16, 0\n\t" \
  "v_bcnt_u32_b32 v18, v17, v18\n\t" \
  "v_lshlrev_b32 v18, 2, v18\n\t" \
  "ds_bpermute_b32 v20, v18, %[vt]\n\t" \
  "global_load_dword " B ", v[24:25], off offset:" OFF "\n\t" \
  "s_waitcnt lgkmcnt(0)\n\t" \
  "v_add_f32 v28, v21, v20\n\t" \
  "v_cmp_gt_f32 vcc, v28, %[thr]\n\t" \
  "v_mul_f32 v29, v28, %[dec]\n\t" \
  "v_cndmask_b32 " BITS ", 0, 1, vcc\n\t" \
  "s_waitcnt vmcnt(31)\n\t" \
  "v_add_f32 v29, v29, " NB "\n\t"

#define BUMPL "v_add_u32 v24, s16, v24\n\t"
#define STOREW(BITS) \
  "global_store_dword v[26:27], " BITS ", off\n\t" \
  "v_add_u32 v26, s17, v26\n\t"

#define BLK(S,S0,BITS) \
  S0("v32","v33","0",BITS) \
  S("v33","v34","256","2",BITS)          S("v34","v35","512","4",BITS) \
  S("v35","v36","768","8",BITS)          S("v36","v37","1024","16",BITS) \
  S("v37","v38","1280","32",BITS)        S("v38","v39","1536","64",BITS) \
  S("v39","v40","1792","0x80",BITS)      S("v40","v41","2048","0x100",BITS) \
  S("v41","v42","2304","0x200",BITS)     S("v42","v43","2560","0x400",BITS) \
  S("v43","v44","2816","0x800",BITS)     S("v44","v45","3072","0x1000",BITS) \
  S("v45","v46","3328","0x2000",BITS)    S("v46","v47","3584","0x4000",BITS) \
  S("v47","v48","3840","0x8000",BITS) \
  BUMPL \
  S("v48","v49","0","0x10000",BITS)      S("v49","v50","256","0x20000",BITS) \
  S("v50","v51","512","0x40000",BITS)    S("v51","v52","768","0x80000",BITS) \
  S("v52","v53","1024","0x100000",BITS)  S("v53","v54","1280","0x200000",BITS) \
  S("v54","v55","1536","0x400000",BITS)  S("v55","v56","1792","0x800000",BITS) \
  S("v56","v57","2048","0x1000000",BITS) S("v57","v58","2304","0x2000000",BITS) \
  S("v58","v59","2560","0x4000000",BITS) S("v59","v60","2816","0x8000000",BITS) \
  S("v60","v61","3072","0x10000000",BITS) S("v61","v62","3328","0x20000000",BITS) \
  S("v62","v63","3584","0x40000000",BITS) S("v63","v32","3840","0x80000000",BITS) \
  BUMPL

#define PRO \
  "v_mov_b32 v24, %[alo]\n\t" "v_mov_b32 v25, %[ahi]\n\t" \
  "v_mov_b32 v26, %[blo]\n\t" "v_mov_b32 v27, %[bhi]\n\t" \
  "s_mov_b32 s16, 0x1000\n\t" "s_mov_b32 s17, 0x100\n\t" \
  "global_load_dword v32, v[24:25], off offset:0\n\t" \
  "global_load_dword v33, v[24:25], off offset:256\n\t" \
  "global_load_dword v34, v[24:25], off offset:512\n\t" \
  "global_load_dword v35, v[24:25], off offset:768\n\t" \
  "global_load_dword v36, v[24:25], off offset:1024\n\t" \
  "global_load_dword v37, v[24:25], off offset:1280\n\t" \
  "global_load_dword v38, v[24:25], off offset:1536\n\t" \
  "global_load_dword v39, v[24:25], off offset:1792\n\t" \
  "global_load_dword v40, v[24:25], off offset:2048\n\t" \
  "global_load_dword v41, v[24:25], off offset:2304\n\t" \
  "global_load_dword v42, v[24:25], off offset:2560\n\t" \
  "global_load_dword v43, v[24:25], off offset:2816\n\t" \
  "global_load_dword v44, v[24:25], off offset:3072\n\t" \
  "global_load_dword v45, v[24:25], off offset:3328\n\t" \
  "global_load_dword v46, v[24:25], off offset:3584\n\t" \
  "global_load_dword v47, v[24:25], off offset:3840\n\t" \
  BUMPL \
  "global_load_dword v48, v[24:25], off offset:0\n\t" \
  "global_load_dword v49, v[24:25], off offset:256\n\t" \
  "global_load_dword v50, v[24:25], off offset:512\n\t" \
  "global_load_dword v51, v[24:25], off offset:768\n\t" \
  "global_load_dword v52, v[24:25], off offset:1024\n\t" \
  "global_load_dword v53, v[24:25], off offset:1280\n\t" \
  "global_load_dword v54, v[24:25], off offset:1536\n\t" \
  "global_load_dword v55, v[24:25], off offset:1792\n\t" \
  "global_load_dword v56, v[24:25], off offset:2048\n\t" \
  "global_load_dword v57, v[24:25], off offset:2304\n\t" \
  "global_load_dword v58, v[24:25], off offset:2560\n\t" \
  "global_load_dword v59, v[24:25], off offset:2816\n\t" \
  "global_load_dword v60, v[24:25], off offset:3072\n\t" \
  "global_load_dword v61, v[24:25], off offset:3328\n\t" \
  "global_load_dword v62, v[24:25], off offset:3584\n\t" \
  "global_load_dword v63, v[24:25], off offset:3840\n\t" \
  BUMPL \
  "s_mov_b64 vcc, 0\n\t" \
  "s_nop 2\n\t" \
  "s_movk_i32 s20, 157\n\t" \
  "s_waitcnt vmcnt(31)\n\t" \
  "v_mov_b32 v29, v32\n\t" \
  "v_mov_b32 v28, 0\n\t"

#define CLOBBERS \
  "v16","v17","v18","v19","v20","v21","v22","v23","v24","v25","v26","v27", \
  "v28","v29","v30","v31","v32","v33","v34","v35","v36","v37","v38","v39", \
  "v40","v41","v42","v43","v44","v45","v46","v47","v48","v49","v50","v51", \
  "v52","v53","v54","v55","v56","v57","v58","v59","v60","v61","v62","v63", \
  "s16","s17","s20","vcc","scc","memory"

__device__ void scan_lin_hot(const float* drive, unsigned* packed,
                             unsigned rlo, unsigned rhi, float p, float dec,
                             float thr, int s) {
    ull a = (ull)drive + (ull)s * 4;
    ull b = (ull)packed + (ull)s * 4;
    asm volatile(
        PRO
        "Lmain%=:\n\t"
        BLK(SL, SL0, "v23") STOREW("v23")
        BLK(SL, SL0, "v30") STOREW("v30")
        "s_add_i32 s20, s20, -1\n\t"
        "s_cmp_lg_u32 s20, 0\n\t"
        "s_cbranch_scc1 Lmain%=\n\t"
        :
        : [alo]"v"((unsigned)a), [ahi]"v"((unsigned)(a >> 32)),
          [blo]"v"((unsigned)b), [bhi]"v"((unsigned)(b >> 32)),
          [rlo]"v"(rlo), [rhi]"v"(rhi), [p]"v"(p), [dec]"v"(dec), [thr]"v"(thr)
        : CLOBBERS);
}

__device__ void scan_bp_hot(const float* drive, unsigned* packed,
                            unsigned rlo, unsigned rhi, float dec,
                            float thr, float vtab, int s) {
    ull a = (ull)drive + (ull)s * 4;
    ull b = (ull)packed + (ull)s * 4;
    asm volatile(
        PRO
        "Lmainb%=:\n\t"
        BLK(SB, SB0, "v23") STOREW("v23")
        BLK(SB, SB0, "v30") STOREW("v30")
        "s_add_i32 s20, s20, -1\n\t"
        "s_cmp_lg_u32 s20, 0\n\t"
        "s_cbranch_scc1 Lmainb%=\n\t"
        :
        : [alo]"v"((unsigned)a), [ahi]"v"((unsigned)(a >> 32)),
          [blo]"v"((unsigned)b), [bhi]"v"((unsigned)(b >> 32)),
          [rlo]"v"(rlo), [rhi]"v"(rhi), [vt]"v"(vtab), [dec]"v"(dec), [thr]"v"(thr)
        : CLOBBERS);
}

// ============ FALLBACK compiled engines (R5-validated) + general slow path ====
#define C_LIN(DK, DK1, LIT) \
  "v_and_b32 %[tlo], vcc_lo, %[crlo]\n\t" \
  "v_and_b32 %[thi], vcc_hi, %[crhi]\n\t" \
  "v_cndmask_b32 %[base], %[w0], %[" DK "], vcc\n\t" \
  "v_bcnt_u32_b32 %[kc], %[tlo], 0\n\t" \
  "v_bcnt_u32_b32 %[kc], %[thi], %[kc]\n\t" \
  "v_cvt_f32_u32 %[kf], %[kc]\n\t" \
  "v_mul_f32 %[acc], %[kf], %[cp]\n\t" \
  "v_add_f32 %[vv], %[base], %[acc]\n\t" \
  "v_cmp_gt_f32 vcc, %[vv], %[cthr]\n\t" \
  "v_mul_f32 %[w0], %[vv], %[cdec]\n\t" \
  "v_add_f32 %[w0], %[w0], %[" DK1 "]\n\t" \
  "v_or_b32 %[tmp], " LIT ", %[bits]\n\t" \
  "v_cndmask_b32 %[bits], %[bits], %[tmp], vcc\n\t"

#define CSTEPS32 \
  C_LIN("d0","d1","1")            C_LIN("d1","d2","2")            C_LIN("d2","d3","4")            C_LIN("d3","d4","8") \
  C_LIN("d4","d5","16")           C_LIN("d5","d6","32")           C_LIN("d6","d7","64")           C_LIN("d7","d8","0x80") \
  C_LIN("d8","d9","0x100")        C_LIN("d9","d10","0x200")       C_LIN("d10","d11","0x400")      C_LIN("d11","d12","0x800") \
  C_LIN("d12","d13","0x1000")     C_LIN("d13","d14","0x2000")     C_LIN("d14","d15","0x4000")     C_LIN("d15","d16","0x8000") \
  C_LIN("d16","d17","0x10000")    C_LIN("d17","d18","0x20000")    C_LIN("d18","d19","0x40000")    C_LIN("d19","d20","0x80000") \
  C_LIN("d20","d21","0x100000")   C_LIN("d21","d22","0x200000")   C_LIN("d22","d23","0x400000")   C_LIN("d23","d24","0x800000") \
  C_LIN("d24","d25","0x1000000")  C_LIN("d25","d26","0x2000000")  C_LIN("d26","d27","0x4000000")  C_LIN("d27","d28","0x8000000") \
  C_LIN("d28","d29","0x10000000") C_LIN("d29","d30","0x20000000") C_LIN("d30","d31","0x40000000") C_LIN("d31","d32","0x80000000")

#define CRUN_BLOCK(B) do { \
    unsigned _tlo, _thi, _kc, _tmp, _bits; float _kf, _acc, _base; \
    ull _mout; \
    asm volatile( \
        "s_mov_b64 vcc, %[min]\n\t" \
        "v_mov_b32 %[bits], 0\n\t" \
        "s_nop 1\n\t" \
        CSTEPS32 \
        "s_mov_b64 %[mout], vcc\n\t" \
        : [vv]"+v"(V), [w0]"+v"(w0), [bits]"=&v"(_bits), [mout]"=s"(_mout), \
          [tlo]"=&v"(_tlo), [thi]"=&v"(_thi), [kc]"=&v"(_kc), [tmp]"=&v"(_tmp), \
          [kf]"=&v"(_kf), [acc]"=&v"(_acc), [base]"=&v"(_base) \
        : [min]"s"(m), [crlo]"v"(row_lo), [crhi]"v"(row_hi), [cp]"v"(p0), \
          [cdec]"v"(decay), [cthr]"v"(thrpos), \
          [d0]"v"(B[0]),  [d1]"v"(B[1]),  [d2]"v"(B[2]),  [d3]"v"(B[3]), \
          [d4]"v"(B[4]),  [d5]"v"(B[5]),  [d6]"v"(B[6]),  [d7]"v"(B[7]), \
          [d8]"v"(B[8]),  [d9]"v"(B[9]),  [d10]"v"(B[10]), [d11]"v"(B[11]), \
          [d12]"v"(B[12]), [d13]"v"(B[13]), [d14]"v"(B[14]), [d15]"v"(B[15]), \
          [d16]"v"(B[16]), [d17]"v"(B[17]), [d18]"v"(B[18]), [d19]"v"(B[19]), \
          [d20]"v"(B[20]), [d21]"v"(B[21]), [d22]"v"(B[22]), [d23]"v"(B[23]), \
          [d24]"v"(B[24]), [d25]"v"(B[25]), [d26]"v"(B[26]), [d27]"v"(B[27]), \
          [d28]"v"(B[28]), [d29]"v"(B[29]), [d30]"v"(B[30]), [d31]"v"(B[31]), \
          [d32]"v"(B[32]) \
        : "vcc"); \
    m = _mout; bitsv = _bits; } while (0)

__device__ void scan_lin_c(const float* drive, unsigned* packed,
                           unsigned row_lo, unsigned row_hi, float p0,
                           float decay, float thrpos, int s) {
    const float* dp = drive + s;
    unsigned* pw = packed + s;
    float bufA[33], bufB[33];
#pragma unroll
    for (int k = 0; k < 33; ++k) bufA[k] = dp[(size_t)k * SUB_NO];
    float V = 0.0f, w0 = bufA[0];
    ull m = 0ull;
    unsigned bitsv;
    for (int b = 0; b < NBLK; b += 2) {
#pragma unroll
        for (int k = 0; k < 33; ++k) bufB[k] = dp[((size_t)(b + 1) * 32 + k) * SUB_NO];
        CRUN_BLOCK(bufA);
        pw[(size_t)b * SUB_NO] = bitsv;
#pragma unroll
        for (int k = 0; k < 33; ++k) bufA[k] = dp[((size_t)(b + 2) * 32 + k) * SUB_NO];
        CRUN_BLOCK(bufB);
        pw[(size_t)(b + 1) * SUB_NO] = bitsv;
    }
}

__device__ void scan_slow(const float* drive, unsigned* packed,
                          ull rowmask, const float* prop_l,
                          float decay, float thr, int s) {
    float V = 0.0f;
    bool sp = false;
    ull mask = 0ull;
    for (int b = 0; b < NBLK; ++b) {
        unsigned bits = 0u;
        for (int k = 0; k < 32; ++k) {
            int t = b * 32 + k;
            float d = drive[(size_t)t * SUB_NO + s];
            ull mm = mask & rowmask;
            float acc = 0.0f;
            for (int j = 0; j < SUB_NO; ++j) {
                float c = ((mm >> j) & 1ull) ? prop_l[j] : 0.0f;
                acc = __fadd_rn(acc, c);
            }
            float Vr = sp ? 0.0f : V;
            float bb = __fmul_rn(Vr, decay);
            float cc = __fadd_rn(bb, d);
            V = __fadd_rn(cc, acc);
            float sv = __fadd_rn(V, thr);
            sp = sv > 0.0f;
            mask = __ballot(sp);
            bits |= sp ? (1u << k) : 0u;
        }
        packed[(size_t)b * SUB_NO + s] = bits;
    }
}

__global__ void __launch_bounds__(64, 1)
scan_kernel(const float* drive, const float* __restrict__ Cden,
            const float* __restrict__ decay_raw, const float* __restrict__ thr_raw,
            const float* __restrict__ prop_raw, unsigned* packed, int fast) {
    __shared__ float prop_l[SUB_NO];
    int s = threadIdx.x;
    prop_l[s] = (float)exp((double)prop_raw[s]);
    __syncthreads();
    float myp = prop_l[s];

    float em = (float)exp(-(double)decay_raw[s]);
    float den = __fadd_rn(1.0f, em);
    float decay = (float)(1.0 / (double)den);
    float thrpos = (float)exp((double)thr_raw[s]);   // |thr|
    float thr = -thrpos;

    ull rowmask = 0ull;
    for (int j = 0; j < SUB_NO; ++j)
        if (Cden[(size_t)s * SUB_NO + j] != 0.0f) rowmask |= (1ull << j);
    unsigned row_lo = (unsigned)rowmask;
    unsigned row_hi = (unsigned)(rowmask >> 32);

    float p0 = prop_l[0];
    bool uni = __all(myp == p0);
    int maxk = (int)__popcll(rowmask);
    for (int off = 32; off; off >>= 1) {
        int o = __shfl_xor(maxk, off);
        maxk = maxk > o ? maxk : o;
    }

    // vtab: lane s holds f(s) = sequential ascending sum of s copies of p0.
    float seqk = 0.0f;
    for (int i = 0; i < s; ++i) seqk = __fadd_rn(seqk, p0);
    float vtab = seqk;

    // linearity: f(k) == RN(k*p) for all reachable k  ->  acc = RN(kc*p)
    bool lok = (s > maxk) || (seqk == __fmul_rn((float)s, p0));
    bool uselin = uni && __all(lok);

    if (uselin && fast)
        scan_lin_hot(drive, packed, row_lo, row_hi, p0, decay, thrpos, s);
    else if (uselin)
        scan_lin_c(drive, packed, row_lo, row_hi, p0, decay, thrpos, s);
    else if (uni && fast)
        scan_bp_hot(drive, packed, row_lo, row_hi, decay, thrpos, vtab, s);
    else
        scan_slow(drive, packed, rowmask, prop_l, decay, thr, s);
}

// ---------------- K3: expand packed bits -> f32 spk_out ----------------
__global__ void expand_kernel(const unsigned* __restrict__ packed,
                              float* __restrict__ spk_out) {
    int idx = blockIdx.x * 256 + threadIdx.x;   // 640000 total
    int t = idx >> 6, s = idx & 63;
    unsigned w = packed[(size_t)(t >> 5) * SUB_NO + s];
    spk_out[idx] = (float)((w >> (t & 31)) & 1u);
}

// ---------------- K4: 201-tap conv of subunit-0 spikes ----------------
__global__ void conv_kernel(const unsigned* __restrict__ packed,
                            float* __restrict__ out) {
    __shared__ float kern_s[KERN_LEN];
    __shared__ float x_s[256 + 2 * PAD];
    int tid = threadIdx.x;
    int t0 = blockIdx.x * 256;

    float e2 = (float)exp(2.0);
    float e075 = (float)exp(0.75);
    for (int m = tid; m < KERN_LEN; m += 256) {
        float tt = (float)m / e2;
        kern_s[m] = __fmul_rn(__fmul_rn(tt, expf(-tt)), e075);
    }
    for (int k = tid; k < 256 + 2 * PAD; k += 256) {
        int idx = t0 - PAD + k;
        float xv = 0.0f;
        if (idx >= 0 && idx < T_DATA) {
            unsigned w = packed[(size_t)(idx >> 5) * SUB_NO];
            xv = (float)((w >> (idx & 31)) & 1u);
        }
        x_s[k] = xv;
    }
    __syncthreads();

    int t = t0 + tid;
    if (t < T_DATA) {
        float acc = 0.0f;
        for (int m = 0; m < KERN_LEN; ++m)
            acc += kern_s[m] * x_s[tid + 2 * PAD - m];
        out[t] = acc;
    }
}

extern "C" void kernel_launch(void* const* d_in, const int* in_sizes, int n_in,
                              void* d_out, int out_size, void* d_ws, size_t ws_size,
                              hipStream_t stream) {
    const float* S_e      = (const float*)d_in[0];
    const float* S_i      = (const float*)d_in[1];
    const float* C_den    = (const float*)d_in[2];
    const float* C_syn_e  = (const float*)d_in[3];
    const float* C_syn_i  = (const float*)d_in[4];
    const float* w_raw    = (const float*)d_in[5];
    const float* dec_raw  = (const float*)d_in[6];
    const float* thr_raw  = (const float*)d_in[7];
    const float* prop_raw = (const float*)d_in[8];

    float* out = (float*)d_out;               // [0,10000) final, [10000,650000) spk_out
    float* ws = (float*)d_ws;
    float* drive = ws;                         // 640000 floats (+ prefetch slack)
    int*   ae    = (int*)(ws + 640000);        // 2000 ints
    int*   ai    = (int*)(ws + 642000);        // 500 ints

    size_t need_bytes = (size_t)(642500 + NBLK * SUB_NO) * 4;
    unsigned* packed = (ws_size >= need_bytes)
                           ? (unsigned*)(ws + 642500)
                           : (unsigned*)ws;

    // hot engines bump 32-bit address words without carry: require the touched
    // windows not to cross a 4GiB boundary (deterministic per capture).
    ull da = (ull)drive, pa = (ull)packed;
    int fast = ((da & 0xFFFFFFFFull) + 0x290000ull <= 0x100000000ull) &&
               ((pa & 0xFFFFFFFFull) + 0x30000ull  <= 0x100000000ull) &&
               (ws_size >= need_bytes);

    assign_kernel<<<(E_NO + I_NO + 255) / 256, 256, 0, stream>>>(C_syn_e, C_syn_i, ae, ai);
    drive_kernel<<<T_DATA, 256, 0, stream>>>(S_e, S_i, w_raw, ae, ai, drive);
    // 256 identical replicas (1 wave/CU): keeps all CUs busy so DVFS holds
    // high SCLK; replicas store identical values to identical addresses.
    scan_kernel<<<256, 64, 0, stream>>>(drive, C_den, dec_raw, thr_raw, prop_raw, packed, fast);
    expand_kernel<<<T_DATA * SUB_NO / 256, 256, 0, stream>>>(packed, out + T_DATA);
    conv_kernel<<<(T_DATA + 255) / 256, 256, 0, stream>>>(packed, out);
}

// Round 8
// 541.636 us; speedup vs baseline: 1.0296x; 1.0296x over previous
//
#include <hip/hip_runtime.h>
#include <math.h>

#define T_DATA 10000
#define E_NO 2000
#define I_NO 500
#define SUB_NO 64
#define KERN_LEN 201
#define PAD 100
#define NBLK 314              // packed words region (314*32 = 10048 steps)
typedef unsigned long long ull;

// ---------------- K0: extract one-hot assignments ----------------
__global__ void assign_kernel(const float* __restrict__ Ce, const float* __restrict__ Ci,
                              int* __restrict__ ae, int* __restrict__ ai) {
    int idx = blockIdx.x * 256 + threadIdx.x;
    if (idx < E_NO) {
        int a = 0;
        for (int s = 0; s < SUB_NO; ++s)
            if (Ce[(size_t)s * E_NO + idx] != 0.0f) a = s;
        ae[idx] = a;
    } else if (idx < E_NO + I_NO) {
        int i = idx - E_NO;
        int a = 0;
        for (int s = 0; s < SUB_NO; ++s)
            if (Ci[(size_t)s * I_NO + i] != 0.0f) a = s;
        ai[i] = a;
    }
}

// ---------------- K1: drive[t][s] = cnt_e*we[s] + cnt_i*wi[s] ----------------
__global__ void drive_kernel(const float* __restrict__ Se, const float* __restrict__ Si,
                             const float* __restrict__ wraw,
                             const int* __restrict__ ae, const int* __restrict__ ai,
                             float* __restrict__ drive) {
    __shared__ float be[SUB_NO];
    __shared__ float bi[SUB_NO];
    int t = blockIdx.x;
    int tid = threadIdx.x;
    if (tid < SUB_NO) { be[tid] = 0.0f; bi[tid] = 0.0f; }
    __syncthreads();
    const float4* se4 = (const float4*)(Se + (size_t)t * E_NO);
    for (int e4 = tid; e4 < E_NO / 4; e4 += 256) {
        float4 v = se4[e4];
        int b = e4 * 4;
        if (v.x != 0.0f) atomicAdd(&be[ae[b + 0]], 1.0f);
        if (v.y != 0.0f) atomicAdd(&be[ae[b + 1]], 1.0f);
        if (v.z != 0.0f) atomicAdd(&be[ae[b + 2]], 1.0f);
        if (v.w != 0.0f) atomicAdd(&be[ae[b + 3]], 1.0f);
    }
    const float4* si4 = (const float4*)(Si + (size_t)t * I_NO);
    for (int i4 = tid; i4 < I_NO / 4; i4 += 256) {
        float4 v = si4[i4];
        int b = i4 * 4;
        if (v.x != 0.0f) atomicAdd(&bi[ai[b + 0]], 1.0f);
        if (v.y != 0.0f) atomicAdd(&bi[ai[b + 1]], 1.0f);
        if (v.z != 0.0f) atomicAdd(&bi[ai[b + 2]], 1.0f);
        if (v.w != 0.0f) atomicAdd(&bi[ai[b + 3]], 1.0f);
    }
    __syncthreads();
    if (tid < SUB_NO) {
        float we = (float)exp((double)wraw[2 * tid]);
        float wi = -(float)exp((double)wraw[2 * tid + 1]);
        drive[(size_t)t * SUB_NO + tid] =
            __fadd_rn(__fmul_rn(be[tid], we), __fmul_rn(bi[tid], wi));
    }
}

// ================= HOT LIN ENGINE v2: stall-filled schedule =================
// Iteration k (k = 0..10048): enters with v28 = V_{k-1}.
//   vcc  = spk_{k-1} = (V_{k-1} > |thr|)        [cmp at step top]
//   w0   = RN(RN(V_{k-1}*dec) + d_k)            [slots 2 & 8]
//   base = spk ? d_k : w0                       [cndmask, vcc read @slot10]
//   V_k  = RN(base + RN(kc*p)), kc = popcnt(vcc & row)
//   bit recorded this iteration = spk_{k-1}  -> records shifted one iteration:
//   prologue iteration 0 records nothing; blocks of 64 record 2 words.
// Every critical link has >=1 independent filler instr; first vcc reader is
// 4 slots after the v_cmp write (hazard wait-states absorbed).

#define BUMPL "v_add_u32 v24, s16, v24\n\t"
#define STOREW(BITS) \
  "global_store_dword v[26:27], " BITS ", off\n\t" \
  "v_add_u32 v26, s17, v26\n\t"

#define QL(B,OFF,LIT,BITS) \
  "v_cmp_gt_f32 vcc, v28, %[thr]\n\t" \
  "v_mul_f32 v29, v28, %[dec]\n\t" \
  "v_or_b32 v22, " LIT ", " BITS "\n\t" \
  "s_waitcnt vmcnt(31)\n\t" \
  "v_and_b32 v16, vcc_lo, %[rlo]\n\t" \
  "v_and_b32 v17, vcc_hi, %[rhi]\n\t" \
  "v_bcnt_u32_b32 v18, v16, 0\n\t" \
  "v_add_f32 v29, v29, " B "\n\t" \
  "v_bcnt_u32_b32 v18, v17, v18\n\t" \
  "v_cndmask_b32 v21, v29, " B ", vcc\n\t" \
  "v_cvt_f32_u32 v19, v18\n\t" \
  "global_load_dword " B ", v[24:25], off offset:" OFF "\n\t" \
  "v_mul_f32 v20, v19, %[p]\n\t" \
  "v_cndmask_b32 " BITS ", " BITS ", v22, vcc\n\t" \
  "v_add_f32 v28, v21, v20\n\t"

#define QL0(B,OFF,BITS) \
  "v_cmp_gt_f32 vcc, v28, %[thr]\n\t" \
  "v_mul_f32 v29, v28, %[dec]\n\t" \
  "s_waitcnt vmcnt(31)\n\t" \
  "v_and_b32 v16, vcc_lo, %[rlo]\n\t" \
  "v_and_b32 v17, vcc_hi, %[rhi]\n\t" \
  "v_bcnt_u32_b32 v18, v16, 0\n\t" \
  "v_add_f32 v29, v29, " B "\n\t" \
  "v_bcnt_u32_b32 v18, v17, v18\n\t" \
  "v_cndmask_b32 v21, v29, " B ", vcc\n\t" \
  "v_cvt_f32_u32 v19, v18\n\t" \
  "global_load_dword " B ", v[24:25], off offset:" OFF "\n\t" \
  "v_mul_f32 v20, v19, %[p]\n\t" \
  "v_cndmask_b32 " BITS ", 0, 1, vcc\n\t" \
  "v_add_f32 v28, v21, v20\n\t"

#define QLP(B,OFF) \
  "v_cmp_gt_f32 vcc, v28, %[thr]\n\t" \
  "v_mul_f32 v29, v28, %[dec]\n\t" \
  "s_waitcnt vmcnt(31)\n\t" \
  "v_and_b32 v16, vcc_lo, %[rlo]\n\t" \
  "v_and_b32 v17, vcc_hi, %[rhi]\n\t" \
  "v_bcnt_u32_b32 v18, v16, 0\n\t" \
  "v_add_f32 v29, v29, " B "\n\t" \
  "v_bcnt_u32_b32 v18, v17, v18\n\t" \
  "v_cndmask_b32 v21, v29, " B ", vcc\n\t" \
  "v_cvt_f32_u32 v19, v18\n\t" \
  "global_load_dword " B ", v[24:25], off offset:" OFF "\n\t" \
  "v_mul_f32 v20, v19, %[p]\n\t" \
  "v_add_f32 v28, v21, v20\n\t"

// 32 record-iterations -> one packed word (bits 0..31 = spk of 32 steps)
#define QHALF(BITS) \
  QL0("v33","256",BITS) \
  QL("v34","512","2",BITS)          QL("v35","768","4",BITS) \
  QL("v36","1024","8",BITS)         QL("v37","1280","16",BITS) \
  QL("v38","1536","32",BITS)        QL("v39","1792","64",BITS) \
  QL("v40","2048","0x80",BITS)      QL("v41","2304","0x100",BITS) \
  QL("v42","2560","0x200",BITS)     QL("v43","2816","0x400",BITS) \
  QL("v44","3072","0x800",BITS)     QL("v45","3328","0x1000",BITS) \
  QL("v46","3584","0x2000",BITS)    QL("v47","3840","0x4000",BITS) \
  BUMPL \
  QL("v48","0","0x8000",BITS) \
  QL("v49","256","0x10000",BITS)    QL("v50","512","0x20000",BITS) \
  QL("v51","768","0x40000",BITS)    QL("v52","1024","0x80000",BITS) \
  QL("v53","1280","0x100000",BITS)  QL("v54","1536","0x200000",BITS) \
  QL("v55","1792","0x400000",BITS)  QL("v56","2048","0x800000",BITS) \
  QL("v57","2304","0x1000000",BITS) QL("v58","2560","0x2000000",BITS) \
  QL("v59","2816","0x4000000",BITS) QL("v60","3072","0x8000000",BITS) \
  QL("v61","3328","0x10000000",BITS) QL("v62","3584","0x20000000",BITS) \
  QL("v63","3840","0x40000000",BITS) \
  BUMPL \
  QL("v32","0","0x80000000",BITS) STOREW(BITS)

#define QPRO \
  "v_mov_b32 v24, %[alo]\n\t" "v_mov_b32 v25, %[ahi]\n\t" \
  "v_mov_b32 v26, %[blo]\n\t" "v_mov_b32 v27, %[bhi]\n\t" \
  "s_mov_b32 s16, 0x1000\n\t" "s_mov_b32 s17, 0x100\n\t" \
  "global_load_dword v32, v[24:25], off offset:0\n\t" \
  "global_load_dword v33, v[24:25], off offset:256\n\t" \
  "global_load_dword v34, v[24:25], off offset:512\n\t" \
  "global_load_dword v35, v[24:25], off offset:768\n\t" \
  "global_load_dword v36, v[24:25], off offset:1024\n\t" \
  "global_load_dword v37, v[24:25], off offset:1280\n\t" \
  "global_load_dword v38, v[24:25], off offset:1536\n\t" \
  "global_load_dword v39, v[24:25], off offset:1792\n\t" \
  "global_load_dword v40, v[24:25], off offset:2048\n\t" \
  "global_load_dword v41, v[24:25], off offset:2304\n\t" \
  "global_load_dword v42, v[24:25], off offset:2560\n\t" \
  "global_load_dword v43, v[24:25], off offset:2816\n\t" \
  "global_load_dword v44, v[24:25], off offset:3072\n\t" \
  "global_load_dword v45, v[24:25], off offset:3328\n\t" \
  "global_load_dword v46, v[24:25], off offset:3584\n\t" \
  "global_load_dword v47, v[24:25], off offset:3840\n\t" \
  BUMPL \
  "global_load_dword v48, v[24:25], off offset:0\n\t" \
  "global_load_dword v49, v[24:25], off offset:256\n\t" \
  "global_load_dword v50, v[24:25], off offset:512\n\t" \
  "global_load_dword v51, v[24:25], off offset:768\n\t" \
  "global_load_dword v52, v[24:25], off offset:1024\n\t" \
  "global_load_dword v53, v[24:25], off offset:1280\n\t" \
  "global_load_dword v54, v[24:25], off offset:1536\n\t" \
  "global_load_dword v55, v[24:25], off offset:1792\n\t" \
  "global_load_dword v56, v[24:25], off offset:2048\n\t" \
  "global_load_dword v57, v[24:25], off offset:2304\n\t" \
  "global_load_dword v58, v[24:25], off offset:2560\n\t" \
  "global_load_dword v59, v[24:25], off offset:2816\n\t" \
  "global_load_dword v60, v[24:25], off offset:3072\n\t" \
  "global_load_dword v61, v[24:25], off offset:3328\n\t" \
  "global_load_dword v62, v[24:25], off offset:3584\n\t" \
  "global_load_dword v63, v[24:25], off offset:3840\n\t" \
  BUMPL \
  "s_movk_i32 s20, 157\n\t" \
  "v_mov_b32 v28, 0\n\t"

#define CLOBBERS \
  "v16","v17","v18","v19","v20","v21","v22","v23","v24","v25","v26","v27", \
  "v28","v29","v30","v31","v32","v33","v34","v35","v36","v37","v38","v39", \
  "v40","v41","v42","v43","v44","v45","v46","v47","v48","v49","v50","v51", \
  "v52","v53","v54","v55","v56","v57","v58","v59","v60","v61","v62","v63", \
  "s16","s17","s20","vcc","scc","memory"

__device__ void scan_lin_hot(const float* drive, unsigned* packed,
                             unsigned rlo, unsigned rhi, float p, float dec,
                             float thr, int s) {
    ull a = (ull)drive + (ull)s * 4;
    ull b = (ull)packed + (ull)s * 4;
    asm volatile(
        QPRO
        QLP("v32","0")                 // iteration 0: computes V_0, no record
        "Lq%=:\n\t"
        QHALF("v23")                   // records 32 spikes -> word, stores
        QHALF("v30")
        "s_add_i32 s20, s20, -1\n\t"
        "s_cmp_lg_u32 s20, 0\n\t"
        "s_cbranch_scc1 Lq%=\n\t"
        :
        : [alo]"v"((unsigned)a), [ahi]"v"((unsigned)(a >> 32)),
          [blo]"v"((unsigned)b), [bhi]"v"((unsigned)(b >> 32)),
          [rlo]"v"(rlo), [rhi]"v"(rhi), [p]"v"(p), [dec]"v"(dec), [thr]"v"(thr)
        : CLOBBERS);
}

// ===== bp fallback engine (R6, validated): uniform p, nonlinear table =====
#define SB(B,NB,OFF,LIT,BITS) \
  "v_and_b32 v16, vcc_lo, %[rlo]\n\t" \
  "v_and_b32 v17, vcc_hi, %[rhi]\n\t" \
  "v_cndmask_b32 v21, v29, " B ", vcc\n\t" \
  "v_bcnt_u32_b32 v18, v16, 0\n\t" \
  "v_bcnt_u32_b32 v18, v17, v18\n\t" \
  "v_lshlrev_b32 v18, 2, v18\n\t" \
  "ds_bpermute_b32 v20, v18, %[vt]\n\t" \
  "global_load_dword " B ", v[24:25], off offset:" OFF "\n\t" \
  "s_waitcnt lgkmcnt(0)\n\t" \
  "v_add_f32 v28, v21, v20\n\t" \
  "v_cmp_gt_f32 vcc, v28, %[thr]\n\t" \
  "v_mul_f32 v29, v28, %[dec]\n\t" \
  "v_add_f32 v29, v29, " NB "\n\t" \
  "v_or_b32 v22, " LIT ", " BITS "\n\t" \
  "v_cndmask_b32 " BITS ", " BITS ", v22, vcc\n\t" \
  "s_waitcnt vmcnt(31)\n\t"

#define SB0(B,NB,OFF,BITS) \
  "v_and_b32 v16, vcc_lo, %[rlo]\n\t" \
  "v_and_b32 v17, vcc_hi, %[rhi]\n\t" \
  "v_cndmask_b32 v21, v29, " B ", vcc\n\t" \
  "v_bcnt_u32_b32 v18, v16, 0\n\t" \
  "v_bcnt_u32_b32 v18, v17, v18\n\t" \
  "v_lshlrev_b32 v18, 2, v18\n\t" \
  "ds_bpermute_b32 v20, v18, %[vt]\n\t" \
  "global_load_dword " B ", v[24:25], off offset:" OFF "\n\t" \
  "s_waitcnt lgkmcnt(0)\n\t" \
  "v_add_f32 v28, v21, v20\n\t" \
  "v_cmp_gt_f32 vcc, v28, %[thr]\n\t" \
  "v_mul_f32 v29, v28, %[dec]\n\t" \
  "v_add_f32 v29, v29, " NB "\n\t" \
  "v_cndmask_b32 " BITS ", 0, 1, vcc\n\t" \
  "s_waitcnt vmcnt(31)\n\t"

#define BBLK(BITS) \
  SB0("v32","v33","0",BITS) \
  SB("v33","v34","256","2",BITS)          SB("v34","v35","512","4",BITS) \
  SB("v35","v36","768","8",BITS)          SB("v36","v37","1024","16",BITS) \
  SB("v37","v38","1280","32",BITS)        SB("v38","v39","1536","64",BITS) \
  SB("v39","v40","1792","0x80",BITS)      SB("v40","v41","2048","0x100",BITS) \
  SB("v41","v42","2304","0x200",BITS)     SB("v42","v43","2560","0x400",BITS) \
  SB("v43","v44","2816","0x800",BITS)     SB("v44","v45","3072","0x1000",BITS) \
  SB("v45","v46","3328","0x2000",BITS)    SB("v46","v47","3584","0x4000",BITS) \
  SB("v47","v48","3840","0x8000",BITS) \
  BUMPL \
  SB("v48","v49","0","0x10000",BITS)      SB("v49","v50","256","0x20000",BITS) \
  SB("v50","v51","512","0x40000",BITS)    SB("v51","v52","768","0x80000",BITS) \
  SB("v52","v53","1024","0x100000",BITS)  SB("v53","v54","1280","0x200000",BITS) \
  SB("v54","v55","1536","0x400000",BITS)  SB("v55","v56","1792","0x800000",BITS) \
  SB("v56","v57","2048","0x1000000",BITS) SB("v57","v58","2304","0x2000000",BITS) \
  SB("v58","v59","2560","0x4000000",BITS) SB("v59","v60","2816","0x8000000",BITS) \
  SB("v60","v61","3072","0x10000000",BITS) SB("v61","v62","3328","0x20000000",BITS) \
  SB("v62","v63","3584","0x40000000",BITS) SB("v63","v32","3840","0x80000000",BITS) \
  BUMPL

__device__ void scan_bp_hot(const float* drive, unsigned* packed,
                            unsigned rlo, unsigned rhi, float dec,
                            float thr, float vtab, int s) {
    ull a = (ull)drive + (ull)s * 4;
    ull b = (ull)packed + (ull)s * 4;
    asm volatile(
        QPRO
        "s_mov_b64 vcc, 0\n\t"
        "s_nop 2\n\t"
        "s_waitcnt vmcnt(31)\n\t"
        "v_mov_b32 v29, v32\n\t"
        "v_mov_b32 v28, 0\n\t"
        "Lb%=:\n\t"
        BBLK("v23") STOREW("v23")
        BBLK("v30") STOREW("v30")
        "s_add_i32 s20, s20, -1\n\t"
        "s_cmp_lg_u32 s20, 0\n\t"
        "s_cbranch_scc1 Lb%=\n\t"
        :
        : [alo]"v"((unsigned)a), [ahi]"v"((unsigned)(a >> 32)),
          [blo]"v"((unsigned)b), [bhi]"v"((unsigned)(b >> 32)),
          [rlo]"v"(rlo), [rhi]"v"(rhi), [vt]"v"(vtab), [dec]"v"(dec), [thr]"v"(thr)
        : CLOBBERS);
}

// ============ compiled fallback (R5-validated) + general slow path ============
#define C_LIN(DK, DK1, LIT) \
  "v_and_b32 %[tlo], vcc_lo, %[crlo]\n\t" \
  "v_and_b32 %[thi], vcc_hi, %[crhi]\n\t" \
  "v_cndmask_b32 %[base], %[w0], %[" DK "], vcc\n\t" \
  "v_bcnt_u32_b32 %[kc], %[tlo], 0\n\t" \
  "v_bcnt_u32_b32 %[kc], %[thi], %[kc]\n\t" \
  "v_cvt_f32_u32 %[kf], %[kc]\n\t" \
  "v_mul_f32 %[acc], %[kf], %[cp]\n\t" \
  "v_add_f32 %[vv], %[base], %[acc]\n\t" \
  "v_cmp_gt_f32 vcc, %[vv], %[cthr]\n\t" \
  "v_mul_f32 %[w0], %[vv], %[cdec]\n\t" \
  "v_add_f32 %[w0], %[w0], %[" DK1 "]\n\t" \
  "v_or_b32 %[tmp], " LIT ", %[bits]\n\t" \
  "v_cndmask_b32 %[bits], %[bits], %[tmp], vcc\n\t"

#define CSTEPS32 \
  C_LIN("d0","d1","1")            C_LIN("d1","d2","2")            C_LIN("d2","d3","4")            C_LIN("d3","d4","8") \
  C_LIN("d4","d5","16")           C_LIN("d5","d6","32")           C_LIN("d6","d7","64")           C_LIN("d7","d8","0x80") \
  C_LIN("d8","d9","0x100")        C_LIN("d9","d10","0x200")       C_LIN("d10","d11","0x400")      C_LIN("d11","d12","0x800") \
  C_LIN("d12","d13","0x1000")     C_LIN("d13","d14","0x2000")     C_LIN("d14","d15","0x4000")     C_LIN("d15","d16","0x8000") \
  C_LIN("d16","d17","0x10000")    C_LIN("d17","d18","0x20000")    C_LIN("d18","d19","0x40000")    C_LIN("d19","d20","0x80000") \
  C_LIN("d20","d21","0x100000")   C_LIN("d21","d22","0x200000")   C_LIN("d22","d23","0x400000")   C_LIN("d23","d24","0x800000") \
  C_LIN("d24","d25","0x1000000")  C_LIN("d25","d26","0x2000000")  C_LIN("d26","d27","0x4000000")  C_LIN("d27","d28","0x8000000") \
  C_LIN("d28","d29","0x10000000") C_LIN("d29","d30","0x20000000") C_LIN("d30","d31","0x40000000") C_LIN("d31","d32","0x80000000")

#define CRUN_BLOCK(B) do { \
    unsigned _tlo, _thi, _kc, _tmp, _bits; float _kf, _acc, _base; \
    ull _mout; \
    asm volatile( \
        "s_mov_b64 vcc, %[min]\n\t" \
        "v_mov_b32 %[bits], 0\n\t" \
        "s_nop 1\n\t" \
        CSTEPS32 \
        "s_mov_b64 %[mout], vcc\n\t" \
        : [vv]"+v"(V), [w0]"+v"(w0), [bits]"=&v"(_bits), [mout]"=s"(_mout), \
          [tlo]"=&v"(_tlo), [thi]"=&v"(_thi), [kc]"=&v"(_kc), [tmp]"=&v"(_tmp), \
          [kf]"=&v"(_kf), [acc]"=&v"(_acc), [base]"=&v"(_base) \
        : [min]"s"(m), [crlo]"v"(row_lo), [crhi]"v"(row_hi), [cp]"v"(p0), \
          [cdec]"v"(decay), [cthr]"v"(thrpos), \
          [d0]"v"(B[0]),  [d1]"v"(B[1]),  [d2]"v"(B[2]),  [d3]"v"(B[3]), \
          [d4]"v"(B[4]),  [d5]"v"(B[5]),  [d6]"v"(B[6]),  [d7]"v"(B[7]), \
          [d8]"v"(B[8]),  [d9]"v"(B[9]),  [d10]"v"(B[10]), [d11]"v"(B[11]), \
          [d12]"v"(B[12]), [d13]"v"(B[13]), [d14]"v"(B[14]), [d15]"v"(B[15]), \
          [d16]"v"(B[16]), [d17]"v"(B[17]), [d18]"v"(B[18]), [d19]"v"(B[19]), \
          [d20]"v"(B[20]), [d21]"v"(B[21]), [d22]"v"(B[22]), [d23]"v"(B[23]), \
          [d24]"v"(B[24]), [d25]"v"(B[25]), [d26]"v"(B[26]), [d27]"v"(B[27]), \
          [d28]"v"(B[28]), [d29]"v"(B[29]), [d30]"v"(B[30]), [d31]"v"(B[31]), \
          [d32]"v"(B[32]) \
        : "vcc"); \
    m = _mout; bitsv = _bits; } while (0)

__device__ void scan_lin_c(const float* drive, unsigned* packed,
                           unsigned row_lo, unsigned row_hi, float p0,
                           float decay, float thrpos, int s) {
    const float* dp = drive + s;
    unsigned* pw = packed + s;
    float bufA[33], bufB[33];
#pragma unroll
    for (int k = 0; k < 33; ++k) bufA[k] = dp[(size_t)k * SUB_NO];
    float V = 0.0f, w0 = bufA[0];
    ull m = 0ull;
    unsigned bitsv;
    for (int b = 0; b < NBLK; b += 2) {
#pragma unroll
        for (int k = 0; k < 33; ++k) bufB[k] = dp[((size_t)(b + 1) * 32 + k) * SUB_NO];
        CRUN_BLOCK(bufA);
        pw[(size_t)b * SUB_NO] = bitsv;
#pragma unroll
        for (int k = 0; k < 33; ++k) bufA[k] = dp[((size_t)(b + 2) * 32 + k) * SUB_NO];
        CRUN_BLOCK(bufB);
        pw[(size_t)(b + 1) * SUB_NO] = bitsv;
    }
}

__device__ void scan_slow(const float* drive, unsigned* packed,
                          ull rowmask, const float* prop_l,
                          float decay, float thr, int s) {
    float V = 0.0f;
    bool sp = false;
    ull mask = 0ull;
    for (int b = 0; b < NBLK; ++b) {
        unsigned bits = 0u;
        for (int k = 0; k < 32; ++k) {
            int t = b * 32 + k;
            float d = drive[(size_t)t * SUB_NO + s];
            ull mm = mask & rowmask;
            float acc = 0.0f;
            for (int j = 0; j < SUB_NO; ++j) {
                float c = ((mm >> j) & 1ull) ? prop_l[j] : 0.0f;
                acc = __fadd_rn(acc, c);
            }
            float Vr = sp ? 0.0f : V;
            float bb = __fmul_rn(Vr, decay);
            float cc = __fadd_rn(bb, d);
            V = __fadd_rn(cc, acc);
            float sv = __fadd_rn(V, thr);
            sp = sv > 0.0f;
            mask = __ballot(sp);
            bits |= sp ? (1u << k) : 0u;
        }
        packed[(size_t)b * SUB_NO + s] = bits;
    }
}

__global__ void __launch_bounds__(64, 1)
scan_kernel(const float* drive, const float* __restrict__ Cden,
            const float* __restrict__ decay_raw, const float* __restrict__ thr_raw,
            const float* __restrict__ prop_raw, unsigned* packed, int fast) {
    __shared__ float prop_l[SUB_NO];
    int s = threadIdx.x;
    prop_l[s] = (float)exp((double)prop_raw[s]);
    __syncthreads();
    float myp = prop_l[s];

    float em = (float)exp(-(double)decay_raw[s]);
    float den = __fadd_rn(1.0f, em);
    float decay = (float)(1.0 / (double)den);
    float thrpos = (float)exp((double)thr_raw[s]);   // |thr|
    float thr = -thrpos;

    ull rowmask = 0ull;
    for (int j = 0; j < SUB_NO; ++j)
        if (Cden[(size_t)s * SUB_NO + j] != 0.0f) rowmask |= (1ull << j);
    unsigned row_lo = (unsigned)rowmask;
    unsigned row_hi = (unsigned)(rowmask >> 32);

    float p0 = prop_l[0];
    bool uni = __all(myp == p0);
    int maxk = (int)__popcll(rowmask);
    for (int off = 32; off; off >>= 1) {
        int o = __shfl_xor(maxk, off);
        maxk = maxk > o ? maxk : o;
    }

    // vtab: lane s holds f(s) = sequential ascending sum of s copies of p0.
    float seqk = 0.0f;
    for (int i = 0; i < s; ++i) seqk = __fadd_rn(seqk, p0);
    float vtab = seqk;

    // linearity: f(k) == RN(k*p) for all reachable k  ->  acc = RN(kc*p)
    bool lok = (s > maxk) || (seqk == __fmul_rn((float)s, p0));
    bool uselin = uni && __all(lok);

    if (uselin && fast)
        scan_lin_hot(drive, packed, row_lo, row_hi, p0, decay, thrpos, s);
    else if (uselin)
        scan_lin_c(drive, packed, row_lo, row_hi, p0, decay, thrpos, s);
    else if (uni && fast)
        scan_bp_hot(drive, packed, row_lo, row_hi, decay, thrpos, vtab, s);
    else
        scan_slow(drive, packed, rowmask, prop_l, decay, thr, s);
}

// ---------------- K3: expand packed bits -> f32 spk_out ----------------
__global__ void expand_kernel(const unsigned* __restrict__ packed,
                              float* __restrict__ spk_out) {
    int idx = blockIdx.x * 256 + threadIdx.x;   // 640000 total
    int t = idx >> 6, s = idx & 63;
    unsigned w = packed[(size_t)(t >> 5) * SUB_NO + s];
    spk_out[idx] = (float)((w >> (t & 31)) & 1u);
}

// ---------------- K4: 201-tap conv of subunit-0 spikes ----------------
__global__ void conv_kernel(const unsigned* __restrict__ packed,
                            float* __restrict__ out) {
    __shared__ float kern_s[KERN_LEN];
    __shared__ float x_s[256 + 2 * PAD];
    int tid = threadIdx.x;
    int t0 = blockIdx.x * 256;

    float e2 = (float)exp(2.0);
    float e075 = (float)exp(0.75);
    for (int m = tid; m < KERN_LEN; m += 256) {
        float tt = (float)m / e2;
        kern_s[m] = __fmul_rn(__fmul_rn(tt, expf(-tt)), e075);
    }
    for (int k = tid; k < 256 + 2 * PAD; k += 256) {
        int idx = t0 - PAD + k;
        float xv = 0.0f;
        if (idx >= 0 && idx < T_DATA) {
            unsigned w = packed[(size_t)(idx >> 5) * SUB_NO];
            xv = (float)((w >> (idx & 31)) & 1u);
        }
        x_s[k] = xv;
    }
    __syncthreads();

    int t = t0 + tid;
    if (t < T_DATA) {
        float acc = 0.0f;
        for (int m = 0; m < KERN_LEN; ++m)
            acc += kern_s[m] * x_s[tid + 2 * PAD - m];
        out[t] = acc;
    }
}

extern "C" void kernel_launch(void* const* d_in, const int* in_sizes, int n_in,
                              void* d_out, int out_size, void* d_ws, size_t ws_size,
                              hipStream_t stream) {
    const float* S_e      = (const float*)d_in[0];
    const float* S_i      = (const float*)d_in[1];
    const float* C_den    = (const float*)d_in[2];
    const float* C_syn_e  = (const float*)d_in[3];
    const float* C_syn_i  = (const float*)d_in[4];
    const float* w_raw    = (const float*)d_in[5];
    const float* dec_raw  = (const float*)d_in[6];
    const float* thr_raw  = (const float*)d_in[7];
    const float* prop_raw = (const float*)d_in[8];

    float* out = (float*)d_out;               // [0,10000) final, [10000,650000) spk_out
    float* ws = (float*)d_ws;
    float* drive = ws;                         // 640000 floats (+ ring over-read slack)
    int*   ae    = (int*)(ws + 640000);        // 2000 ints
    int*   ai    = (int*)(ws + 642000);        // 500 ints

    size_t need_bytes = (size_t)(642500 + NBLK * SUB_NO) * 4;
    unsigned* packed = (ws_size >= need_bytes)
                           ? (unsigned*)(ws + 642500)
                           : (unsigned*)ws;

    // hot engines bump 32-bit address words without carry: require the touched
    // windows not to cross a 4GiB boundary (deterministic per capture).
    ull da = (ull)drive, pa = (ull)packed;
    int fast = ((da & 0xFFFFFFFFull) + 0x290000ull <= 0x100000000ull) &&
               ((pa & 0xFFFFFFFFull) + 0x30000ull  <= 0x100000000ull) &&
               (ws_size >= need_bytes);

    assign_kernel<<<(E_NO + I_NO + 255) / 256, 256, 0, stream>>>(C_syn_e, C_syn_i, ae, ai);
    drive_kernel<<<T_DATA, 256, 0, stream>>>(S_e, S_i, w_raw, ae, ai, drive);
    scan_kernel<<<1, 64, 0, stream>>>(drive, C_den, dec_raw, thr_raw, prop_raw, packed, fast);
    expand_kernel<<<T_DATA * SUB_NO / 256, 256, 0, stream>>>(packed, out + T_DATA);
    conv_kernel<<<(T_DATA + 255) / 256, 256, 0, stream>>>(packed, out);
}

// Round 9
// 527.124 us; speedup vs baseline: 1.0580x; 1.0275x over previous
//
#include <hip/hip_runtime.h>
#include <math.h>

#define T_DATA 10000
#define E_NO 2000
#define I_NO 500
#define SUB_NO 64
#define KERN_LEN 201
#define PAD 100
#define NBLK 314              // packed words (314*32 = 10048 recorded steps)
#define TSTRIDE 10112         // drive_T row stride (floats), 16B-aligned, ring slack
typedef unsigned long long ull;

// ---------------- K0: extract one-hot assignments ----------------
__global__ void assign_kernel(const float* __restrict__ Ce, const float* __restrict__ Ci,
                              int* __restrict__ ae, int* __restrict__ ai) {
    int idx = blockIdx.x * 256 + threadIdx.x;
    if (idx < E_NO) {
        int a = 0;
        for (int s = 0; s < SUB_NO; ++s)
            if (Ce[(size_t)s * E_NO + idx] != 0.0f) a = s;
        ae[idx] = a;
    } else if (idx < E_NO + I_NO) {
        int i = idx - E_NO;
        int a = 0;
        for (int s = 0; s < SUB_NO; ++s)
            if (Ci[(size_t)s * I_NO + i] != 0.0f) a = s;
        ai[i] = a;
    }
}

// ---------------- K1: drive[t][s] = cnt_e*we[s] + cnt_i*wi[s] ----------------
__global__ void drive_kernel(const float* __restrict__ Se, const float* __restrict__ Si,
                             const float* __restrict__ wraw,
                             const int* __restrict__ ae, const int* __restrict__ ai,
                             float* __restrict__ drive) {
    __shared__ float be[SUB_NO];
    __shared__ float bi[SUB_NO];
    int t = blockIdx.x;
    int tid = threadIdx.x;
    if (tid < SUB_NO) { be[tid] = 0.0f; bi[tid] = 0.0f; }
    __syncthreads();
    const float4* se4 = (const float4*)(Se + (size_t)t * E_NO);
    for (int e4 = tid; e4 < E_NO / 4; e4 += 256) {
        float4 v = se4[e4];
        int b = e4 * 4;
        if (v.x != 0.0f) atomicAdd(&be[ae[b + 0]], 1.0f);
        if (v.y != 0.0f) atomicAdd(&be[ae[b + 1]], 1.0f);
        if (v.z != 0.0f) atomicAdd(&be[ae[b + 2]], 1.0f);
        if (v.w != 0.0f) atomicAdd(&be[ae[b + 3]], 1.0f);
    }
    const float4* si4 = (const float4*)(Si + (size_t)t * I_NO);
    for (int i4 = tid; i4 < I_NO / 4; i4 += 256) {
        float4 v = si4[i4];
        int b = i4 * 4;
        if (v.x != 0.0f) atomicAdd(&bi[ai[b + 0]], 1.0f);
        if (v.y != 0.0f) atomicAdd(&bi[ai[b + 1]], 1.0f);
        if (v.z != 0.0f) atomicAdd(&bi[ai[b + 2]], 1.0f);
        if (v.w != 0.0f) atomicAdd(&bi[ai[b + 3]], 1.0f);
    }
    __syncthreads();
    if (tid < SUB_NO) {
        float we = (float)exp((double)wraw[2 * tid]);
        float wi = -(float)exp((double)wraw[2 * tid + 1]);
        drive[(size_t)t * SUB_NO + tid] =
            __fadd_rn(__fmul_rn(be[tid], we), __fmul_rn(bi[tid], wi));
    }
}

// ---------------- K1b: transpose drive[t][s] -> drive_T[s][t] ----------------
__global__ void transpose_kernel(const float* __restrict__ drive,
                                 float* __restrict__ dT) {
    __shared__ float tile[64][65];          // +1 pad: conflict-free both phases
    int t0 = blockIdx.x * 64;
    int w = threadIdx.x;                    // 256 threads
    for (int k = 0; k < 16; ++k) {
        int L = w + 256 * k;                // coalesced read
        int i = L >> 6, s = L & 63;
        int t = t0 + i;
        tile[i][s] = (t < T_DATA) ? drive[(size_t)t * SUB_NO + s] : 0.0f;
    }
    __syncthreads();
    int l = w & 63, g = w >> 6;
    for (int k = 0; k < 16; ++k) {
        int s = g * 16 + k;
        dT[(size_t)s * TSTRIDE + t0 + l] = tile[l][s];  // coalesced 256B write
    }
}

// ========== HOT ENGINES v3: transposed layout, dwordx4 quad ring ==========
// Ring: 8 quads v[32:35]..v[60:63] = 32 steps in flight; 1 load / 4 steps;
// counted s_waitcnt vmcnt(7) (never drains). Step body = R8-validated
// bit-exact core. Iteration k enters with v28=V_{k-1}; vcc=spk_{k-1} is
// recomputed at step top; records spk_{k-1} (one-iteration shift, prologue
// records nothing).

#define W7 "s_waitcnt vmcnt(7)\n\t"
#define LOADQ(Q) \
  "global_load_dwordx4 " Q ", v[24:25], off\n\t" \
  "v_add_u32 v24, 16, v24\n\t"
#define STOREW(BITS) \
  "global_store_dword v[26:27], " BITS ", off\n\t" \
  "v_add_u32 v26, s17, v26\n\t"

#define QS(D,LIT,BITS) \
  "v_cmp_gt_f32 vcc, v28, %[thr]\n\t" \
  "v_mul_f32 v29, v28, %[dec]\n\t" \
  "v_or_b32 v22, " LIT ", " BITS "\n\t" \
  "v_and_b32 v16, vcc_lo, %[rlo]\n\t" \
  "v_and_b32 v17, vcc_hi, %[rhi]\n\t" \
  "v_add_f32 v29, v29, " D "\n\t" \
  "v_bcnt_u32_b32 v18, v16, 0\n\t" \
  "v_bcnt_u32_b32 v18, v17, v18\n\t" \
  "v_cndmask_b32 v21, v29, " D ", vcc\n\t" \
  "v_cvt_f32_u32 v19, v18\n\t" \
  "v_cndmask_b32 " BITS ", " BITS ", v22, vcc\n\t" \
  "v_mul_f32 v20, v19, %[p]\n\t" \
  "v_add_f32 v28, v21, v20\n\t"

#define QS0(D,BITS) \
  "v_cmp_gt_f32 vcc, v28, %[thr]\n\t" \
  "v_mul_f32 v29, v28, %[dec]\n\t" \
  "v_and_b32 v16, vcc_lo, %[rlo]\n\t" \
  "v_and_b32 v17, vcc_hi, %[rhi]\n\t" \
  "v_add_f32 v29, v29, " D "\n\t" \
  "v_bcnt_u32_b32 v18, v16, 0\n\t" \
  "v_bcnt_u32_b32 v18, v17, v18\n\t" \
  "v_cndmask_b32 v21, v29, " D ", vcc\n\t" \
  "v_cvt_f32_u32 v19, v18\n\t" \
  "v_cndmask_b32 " BITS ", 0, 1, vcc\n\t" \
  "v_mul_f32 v20, v19, %[p]\n\t" \
  "v_add_f32 v28, v21, v20\n\t"

#define QSP(D) \
  "v_cmp_gt_f32 vcc, v28, %[thr]\n\t" \
  "v_mul_f32 v29, v28, %[dec]\n\t" \
  "v_and_b32 v16, vcc_lo, %[rlo]\n\t" \
  "v_and_b32 v17, vcc_hi, %[rhi]\n\t" \
  "v_add_f32 v29, v29, " D "\n\t" \
  "v_bcnt_u32_b32 v18, v16, 0\n\t" \
  "v_bcnt_u32_b32 v18, v17, v18\n\t" \
  "v_cndmask_b32 v21, v29, " D ", vcc\n\t" \
  "v_cvt_f32_u32 v19, v18\n\t" \
  "v_mul_f32 v20, v19, %[p]\n\t" \
  "v_add_f32 v28, v21, v20\n\t"

#define GRP(BITS) \
  W7 QS0("v33",BITS) QS("v34","2",BITS) QS("v35","4",BITS) LOADQ("v[32:35]") \
  W7 QS("v36","8",BITS) QS("v37","16",BITS) QS("v38","32",BITS) QS("v39","64",BITS) LOADQ("v[36:39]") \
  W7 QS("v40","0x80",BITS) QS("v41","0x100",BITS) QS("v42","0x200",BITS) QS("v43","0x400",BITS) LOADQ("v[40:43]") \
  W7 QS("v44","0x800",BITS) QS("v45","0x1000",BITS) QS("v46","0x2000",BITS) QS("v47","0x4000",BITS) LOADQ("v[44:47]") \
  W7 QS("v48","0x8000",BITS) QS("v49","0x10000",BITS) QS("v50","0x20000",BITS) QS("v51","0x40000",BITS) LOADQ("v[48:51]") \
  W7 QS("v52","0x80000",BITS) QS("v53","0x100000",BITS) QS("v54","0x200000",BITS) QS("v55","0x400000",BITS) LOADQ("v[52:55]") \
  W7 QS("v56","0x800000",BITS) QS("v57","0x1000000",BITS) QS("v58","0x2000000",BITS) QS("v59","0x4000000",BITS) LOADQ("v[56:59]") \
  W7 QS("v60","0x8000000",BITS) QS("v61","0x10000000",BITS) QS("v62","0x20000000",BITS) QS("v63","0x40000000",BITS) LOADQ("v[60:63]") \
  W7 QS("v32","0x80000000",BITS) \
  STOREW(BITS)

// bp variant (uniform p, nonlinear seq-sum table in lanes of vt)
#define QSB(D,LIT,BITS) \
  "v_cmp_gt_f32 vcc, v28, %[thr]\n\t" \
  "v_or_b32 v22, " LIT ", " BITS "\n\t" \
  "v_mul_f32 v29, v28, %[dec]\n\t" \
  "v_and_b32 v16, vcc_lo, %[rlo]\n\t" \
  "v_and_b32 v17, vcc_hi, %[rhi]\n\t" \
  "v_add_f32 v29, v29, " D "\n\t" \
  "v_bcnt_u32_b32 v18, v16, 0\n\t" \
  "v_bcnt_u32_b32 v18, v17, v18\n\t" \
  "v_lshlrev_b32 v18, 2, v18\n\t" \
  "ds_bpermute_b32 v20, v18, %[vt]\n\t" \
  "v_cndmask_b32 v21, v29, " D ", vcc\n\t" \
  "v_cndmask_b32 " BITS ", " BITS ", v22, vcc\n\t" \
  "s_waitcnt lgkmcnt(0)\n\t" \
  "v_add_f32 v28, v21, v20\n\t"

#define QSB0(D,BITS) \
  "v_cmp_gt_f32 vcc, v28, %[thr]\n\t" \
  "v_mul_f32 v29, v28, %[dec]\n\t" \
  "v_and_b32 v16, vcc_lo, %[rlo]\n\t" \
  "v_and_b32 v17, vcc_hi, %[rhi]\n\t" \
  "v_add_f32 v29, v29, " D "\n\t" \
  "v_bcnt_u32_b32 v18, v16, 0\n\t" \
  "v_bcnt_u32_b32 v18, v17, v18\n\t" \
  "v_lshlrev_b32 v18, 2, v18\n\t" \
  "ds_bpermute_b32 v20, v18, %[vt]\n\t" \
  "v_cndmask_b32 v21, v29, " D ", vcc\n\t" \
  "v_cndmask_b32 " BITS ", 0, 1, vcc\n\t" \
  "s_waitcnt lgkmcnt(0)\n\t" \
  "v_add_f32 v28, v21, v20\n\t"

#define QSBP(D) \
  "v_cmp_gt_f32 vcc, v28, %[thr]\n\t" \
  "v_mul_f32 v29, v28, %[dec]\n\t" \
  "v_and_b32 v16, vcc_lo, %[rlo]\n\t" \
  "v_and_b32 v17, vcc_hi, %[rhi]\n\t" \
  "v_add_f32 v29, v29, " D "\n\t" \
  "v_bcnt_u32_b32 v18, v16, 0\n\t" \
  "v_bcnt_u32_b32 v18, v17, v18\n\t" \
  "v_lshlrev_b32 v18, 2, v18\n\t" \
  "ds_bpermute_b32 v20, v18, %[vt]\n\t" \
  "v_cndmask_b32 v21, v29, " D ", vcc\n\t" \
  "s_waitcnt lgkmcnt(0)\n\t" \
  "v_add_f32 v28, v21, v20\n\t"

#define GRPB(BITS) \
  W7 QSB0("v33",BITS) QSB("v34","2",BITS) QSB("v35","4",BITS) LOADQ("v[32:35]") \
  W7 QSB("v36","8",BITS) QSB("v37","16",BITS) QSB("v38","32",BITS) QSB("v39","64",BITS) LOADQ("v[36:39]") \
  W7 QSB("v40","0x80",BITS) QSB("v41","0x100",BITS) QSB("v42","0x200",BITS) QSB("v43","0x400",BITS) LOADQ("v[40:43]") \
  W7 QSB("v44","0x800",BITS) QSB("v45","0x1000",BITS) QSB("v46","0x2000",BITS) QSB("v47","0x4000",BITS) LOADQ("v[44:47]") \
  W7 QSB("v48","0x8000",BITS) QSB("v49","0x10000",BITS) QSB("v50","0x20000",BITS) QSB("v51","0x40000",BITS) LOADQ("v[48:51]") \
  W7 QSB("v52","0x80000",BITS) QSB("v53","0x100000",BITS) QSB("v54","0x200000",BITS) QSB("v55","0x400000",BITS) LOADQ("v[52:55]") \
  W7 QSB("v56","0x800000",BITS) QSB("v57","0x1000000",BITS) QSB("v58","0x2000000",BITS) QSB("v59","0x4000000",BITS) LOADQ("v[56:59]") \
  W7 QSB("v60","0x8000000",BITS) QSB("v61","0x10000000",BITS) QSB("v62","0x20000000",BITS) QSB("v63","0x40000000",BITS) LOADQ("v[60:63]") \
  W7 QSB("v32","0x80000000",BITS) \
  STOREW(BITS)

#define VPRO \
  "v_mov_b32 v24, %[alo]\n\t" "v_mov_b32 v25, %[ahi]\n\t" \
  "v_mov_b32 v26, %[blo]\n\t" "v_mov_b32 v27, %[bhi]\n\t" \
  "s_mov_b32 s17, 0x100\n\t" \
  LOADQ("v[32:35]") LOADQ("v[36:39]") LOADQ("v[40:43]") LOADQ("v[44:47]") \
  LOADQ("v[48:51]") LOADQ("v[52:55]") LOADQ("v[56:59]") LOADQ("v[60:63]") \
  "s_movk_i32 s20, 157\n\t" \
  "v_mov_b32 v28, 0\n\t" \
  W7

#define CLOBBERS \
  "v16","v17","v18","v19","v20","v21","v22","v23","v24","v25","v26","v27", \
  "v28","v29","v30","v31","v32","v33","v34","v35","v36","v37","v38","v39", \
  "v40","v41","v42","v43","v44","v45","v46","v47","v48","v49","v50","v51", \
  "v52","v53","v54","v55","v56","v57","v58","v59","v60","v61","v62","v63", \
  "s17","s20","vcc","scc","memory"

__device__ void scan_linT_hot(const float* dT, unsigned* packed,
                              unsigned rlo, unsigned rhi, float p, float dec,
                              float thr, int s) {
    ull a = (ull)dT + (ull)s * (TSTRIDE * 4);   // lane row base
    ull b = (ull)packed + (ull)s * 4;
    asm volatile(
        VPRO
        QSP("v32")                   // t=0, records nothing
        "Lt%=:\n\t"
        GRP("v23")
        GRP("v30")
        "s_add_i32 s20, s20, -1\n\t"
        "s_cmp_lg_u32 s20, 0\n\t"
        "s_cbranch_scc1 Lt%=\n\t"
        :
        : [alo]"v"((unsigned)a), [ahi]"v"((unsigned)(a >> 32)),
          [blo]"v"((unsigned)b), [bhi]"v"((unsigned)(b >> 32)),
          [rlo]"v"(rlo), [rhi]"v"(rhi), [p]"v"(p), [dec]"v"(dec), [thr]"v"(thr)
        : CLOBBERS);
}

__device__ void scan_bpT_hot(const float* dT, unsigned* packed,
                             unsigned rlo, unsigned rhi, float dec,
                             float thr, float vtab, int s) {
    ull a = (ull)dT + (ull)s * (TSTRIDE * 4);
    ull b = (ull)packed + (ull)s * 4;
    asm volatile(
        VPRO
        QSBP("v32")
        "Lu%=:\n\t"
        GRPB("v23")
        GRPB("v30")
        "s_add_i32 s20, s20, -1\n\t"
        "s_cmp_lg_u32 s20, 0\n\t"
        "s_cbranch_scc1 Lu%=\n\t"
        :
        : [alo]"v"((unsigned)a), [ahi]"v"((unsigned)(a >> 32)),
          [blo]"v"((unsigned)b), [bhi]"v"((unsigned)(b >> 32)),
          [rlo]"v"(rlo), [rhi]"v"(rhi), [vt]"v"(vtab), [dec]"v"(dec), [thr]"v"(thr)
        : CLOBBERS);
}

// ============ compiled fallback (R5-validated) + general slow path ============
#define C_LIN(DK, DK1, LIT) \
  "v_and_b32 %[tlo], vcc_lo, %[crlo]\n\t" \
  "v_and_b32 %[thi], vcc_hi, %[crhi]\n\t" \
  "v_cndmask_b32 %[base], %[w0], %[" DK "], vcc\n\t" \
  "v_bcnt_u32_b32 %[kc], %[tlo], 0\n\t" \
  "v_bcnt_u32_b32 %[kc], %[thi], %[kc]\n\t" \
  "v_cvt_f32_u32 %[kf], %[kc]\n\t" \
  "v_mul_f32 %[acc], %[kf], %[cp]\n\t" \
  "v_add_f32 %[vv], %[base], %[acc]\n\t" \
  "v_cmp_gt_f32 vcc, %[vv], %[cthr]\n\t" \
  "v_mul_f32 %[w0], %[vv], %[cdec]\n\t" \
  "v_add_f32 %[w0], %[w0], %[" DK1 "]\n\t" \
  "v_or_b32 %[tmp], " LIT ", %[bits]\n\t" \
  "v_cndmask_b32 %[bits], %[bits], %[tmp], vcc\n\t"

#define CSTEPS32 \
  C_LIN("d0","d1","1")            C_LIN("d1","d2","2")            C_LIN("d2","d3","4")            C_LIN("d3","d4","8") \
  C_LIN("d4","d5","16")           C_LIN("d5","d6","32")           C_LIN("d6","d7","64")           C_LIN("d7","d8","0x80") \
  C_LIN("d8","d9","0x100")        C_LIN("d9","d10","0x200")       C_LIN("d10","d11","0x400")      C_LIN("d11","d12","0x800") \
  C_LIN("d12","d13","0x1000")     C_LIN("d13","d14","0x2000")     C_LIN("d14","d15","0x4000")     C_LIN("d15","d16","0x8000") \
  C_LIN("d16","d17","0x10000")    C_LIN("d17","d18","0x20000")    C_LIN("d18","d19","0x40000")    C_LIN("d19","d20","0x80000") \
  C_LIN("d20","d21","0x100000")   C_LIN("d21","d22","0x200000")   C_LIN("d22","d23","0x400000")   C_LIN("d23","d24","0x800000") \
  C_LIN("d24","d25","0x1000000")  C_LIN("d25","d26","0x2000000")  C_LIN("d26","d27","0x4000000")  C_LIN("d27","d28","0x8000000") \
  C_LIN("d28","d29","0x10000000") C_LIN("d29","d30","0x20000000") C_LIN("d30","d31","0x40000000") C_LIN("d31","d32","0x80000000")

#define CRUN_BLOCK(B) do { \
    unsigned _tlo, _thi, _kc, _tmp, _bits; float _kf, _acc, _base; \
    ull _mout; \
    asm volatile( \
        "s_mov_b64 vcc, %[min]\n\t" \
        "v_mov_b32 %[bits], 0\n\t" \
        "s_nop 1\n\t" \
        CSTEPS32 \
        "s_mov_b64 %[mout], vcc\n\t" \
        : [vv]"+v"(V), [w0]"+v"(w0), [bits]"=&v"(_bits), [mout]"=s"(_mout), \
          [tlo]"=&v"(_tlo), [thi]"=&v"(_thi), [kc]"=&v"(_kc), [tmp]"=&v"(_tmp), \
          [kf]"=&v"(_kf), [acc]"=&v"(_acc), [base]"=&v"(_base) \
        : [min]"s"(m), [crlo]"v"(row_lo), [crhi]"v"(row_hi), [cp]"v"(p0), \
          [cdec]"v"(decay), [cthr]"v"(thrpos), \
          [d0]"v"(B[0]),  [d1]"v"(B[1]),  [d2]"v"(B[2]),  [d3]"v"(B[3]), \
          [d4]"v"(B[4]),  [d5]"v"(B[5]),  [d6]"v"(B[6]),  [d7]"v"(B[7]), \
          [d8]"v"(B[8]),  [d9]"v"(B[9]),  [d10]"v"(B[10]), [d11]"v"(B[11]), \
          [d12]"v"(B[12]), [d13]"v"(B[13]), [d14]"v"(B[14]), [d15]"v"(B[15]), \
          [d16]"v"(B[16]), [d17]"v"(B[17]), [d18]"v"(B[18]), [d19]"v"(B[19]), \
          [d20]"v"(B[20]), [d21]"v"(B[21]), [d22]"v"(B[22]), [d23]"v"(B[23]), \
          [d24]"v"(B[24]), [d25]"v"(B[25]), [d26]"v"(B[26]), [d27]"v"(B[27]), \
          [d28]"v"(B[28]), [d29]"v"(B[29]), [d30]"v"(B[30]), [d31]"v"(B[31]), \
          [d32]"v"(B[32]) \
        : "vcc"); \
    m = _mout; bitsv = _bits; } while (0)

__device__ void scan_lin_c(const float* drive, unsigned* packed,
                           unsigned row_lo, unsigned row_hi, float p0,
                           float decay, float thrpos, int s) {
    const float* dp = drive + s;
    unsigned* pw = packed + s;
    float bufA[33], bufB[33];
#pragma unroll
    for (int k = 0; k < 33; ++k) bufA[k] = dp[(size_t)k * SUB_NO];
    float V = 0.0f, w0 = bufA[0];
    ull m = 0ull;
    unsigned bitsv;
    for (int b = 0; b < NBLK; b += 2) {
#pragma unroll
        for (int k = 0; k < 33; ++k) bufB[k] = dp[((size_t)(b + 1) * 32 + k) * SUB_NO];
        CRUN_BLOCK(bufA);
        pw[(size_t)b * SUB_NO] = bitsv;
#pragma unroll
        for (int k = 0; k < 33; ++k) bufA[k] = dp[((size_t)(b + 2) * 32 + k) * SUB_NO];
        CRUN_BLOCK(bufB);
        pw[(size_t)(b + 1) * SUB_NO] = bitsv;
    }
}

__device__ void scan_slow(const float* drive, unsigned* packed,
                          ull rowmask, const float* prop_l,
                          float decay, float thr, int s) {
    float V = 0.0f;
    bool sp = false;
    ull mask = 0ull;
    for (int b = 0; b < NBLK; ++b) {
        unsigned bits = 0u;
        for (int k = 0; k < 32; ++k) {
            int t = b * 32 + k;
            float d = drive[(size_t)t * SUB_NO + s];
            ull mm = mask & rowmask;
            float acc = 0.0f;
            for (int j = 0; j < SUB_NO; ++j) {
                float c = ((mm >> j) & 1ull) ? prop_l[j] : 0.0f;
                acc = __fadd_rn(acc, c);
            }
            float Vr = sp ? 0.0f : V;
            float bb = __fmul_rn(Vr, decay);
            float cc = __fadd_rn(bb, d);
            V = __fadd_rn(cc, acc);
            float sv = __fadd_rn(V, thr);
            sp = sv > 0.0f;
            mask = __ballot(sp);
            bits |= sp ? (1u << k) : 0u;
        }
        packed[(size_t)b * SUB_NO + s] = bits;
    }
}

__global__ void __launch_bounds__(64, 1)
scan_kernel(const float* drive, const float* dT, const float* __restrict__ Cden,
            const float* __restrict__ decay_raw, const float* __restrict__ thr_raw,
            const float* __restrict__ prop_raw, unsigned* packed, int fast) {
    __shared__ float prop_l[SUB_NO];
    int s = threadIdx.x;
    prop_l[s] = (float)exp((double)prop_raw[s]);
    __syncthreads();
    float myp = prop_l[s];

    float em = (float)exp(-(double)decay_raw[s]);
    float den = __fadd_rn(1.0f, em);
    float decay = (float)(1.0 / (double)den);
    float thrpos = (float)exp((double)thr_raw[s]);   // |thr|
    float thr = -thrpos;

    ull rowmask = 0ull;
    for (int j = 0; j < SUB_NO; ++j)
        if (Cden[(size_t)s * SUB_NO + j] != 0.0f) rowmask |= (1ull << j);
    unsigned row_lo = (unsigned)rowmask;
    unsigned row_hi = (unsigned)(rowmask >> 32);

    float p0 = prop_l[0];
    bool uni = __all(myp == p0);
    int maxk = (int)__popcll(rowmask);
    for (int off = 32; off; off >>= 1) {
        int o = __shfl_xor(maxk, off);
        maxk = maxk > o ? maxk : o;
    }

    // vtab: lane s holds f(s) = sequential ascending sum of s copies of p0.
    float seqk = 0.0f;
    for (int i = 0; i < s; ++i) seqk = __fadd_rn(seqk, p0);
    float vtab = seqk;

    // linearity: f(k) == RN(k*p) for all reachable k  ->  acc = RN(kc*p)
    bool lok = (s > maxk) || (seqk == __fmul_rn((float)s, p0));
    bool uselin = uni && __all(lok);

    if (uselin && fast)
        scan_linT_hot(dT, packed, row_lo, row_hi, p0, decay, thrpos, s);
    else if (uni && fast)
        scan_bpT_hot(dT, packed, row_lo, row_hi, decay, thrpos, vtab, s);
    else if (uselin)
        scan_lin_c(drive, packed, row_lo, row_hi, p0, decay, thrpos, s);
    else
        scan_slow(drive, packed, rowmask, prop_l, decay, thr, s);
}

// ---------------- K3: expand packed bits -> f32 spk_out ----------------
__global__ void expand_kernel(const unsigned* __restrict__ packed,
                              float* __restrict__ spk_out) {
    int idx = blockIdx.x * 256 + threadIdx.x;   // 640000 total
    int t = idx >> 6, s = idx & 63;
    unsigned w = packed[(size_t)(t >> 5) * SUB_NO + s];
    spk_out[idx] = (float)((w >> (t & 31)) & 1u);
}

// ---------------- K4: 201-tap conv of subunit-0 spikes ----------------
__global__ void conv_kernel(const unsigned* __restrict__ packed,
                            float* __restrict__ out) {
    __shared__ float kern_s[KERN_LEN];
    __shared__ float x_s[256 + 2 * PAD];
    int tid = threadIdx.x;
    int t0 = blockIdx.x * 256;

    float e2 = (float)exp(2.0);
    float e075 = (float)exp(0.75);
    for (int m = tid; m < KERN_LEN; m += 256) {
        float tt = (float)m / e2;
        kern_s[m] = __fmul_rn(__fmul_rn(tt, expf(-tt)), e075);
    }
    for (int k = tid; k < 256 + 2 * PAD; k += 256) {
        int idx = t0 - PAD + k;
        float xv = 0.0f;
        if (idx >= 0 && idx < T_DATA) {
            unsigned w = packed[(size_t)(idx >> 5) * SUB_NO];
            xv = (float)((w >> (idx & 31)) & 1u);
        }
        x_s[k] = xv;
    }
    __syncthreads();

    int t = t0 + tid;
    if (t < T_DATA) {
        float acc = 0.0f;
        for (int m = 0; m < KERN_LEN; ++m)
            acc += kern_s[m] * x_s[tid + 2 * PAD - m];
        out[t] = acc;
    }
}

extern "C" void kernel_launch(void* const* d_in, const int* in_sizes, int n_in,
                              void* d_out, int out_size, void* d_ws, size_t ws_size,
                              hipStream_t stream) {
    const float* S_e      = (const float*)d_in[0];
    const float* S_i      = (const float*)d_in[1];
    const float* C_den    = (const float*)d_in[2];
    const float* C_syn_e  = (const float*)d_in[3];
    const float* C_syn_i  = (const float*)d_in[4];
    const float* w_raw    = (const float*)d_in[5];
    const float* dec_raw  = (const float*)d_in[6];
    const float* thr_raw  = (const float*)d_in[7];
    const float* prop_raw = (const float*)d_in[8];

    float* out = (float*)d_out;               // [0,10000) final, [10000,650000) spk_out
    float* ws = (float*)d_ws;
    float* drive = ws;                         // 640000 floats
    int*   ae    = (int*)(ws + 640000);        // 2000 ints
    int*   ai    = (int*)(ws + 642000);        // 500 ints

    size_t need_bytes = (size_t)(642500 + NBLK * SUB_NO) * 4;
    unsigned* packed = (ws_size >= need_bytes)
                           ? (unsigned*)(ws + 642500)
                           : (unsigned*)ws;

    // drive_T[s][TSTRIDE] lives in d_out scratch space: [2832, 650000) floats.
    // Written by transpose (before scan); overwritten later by expand/conv,
    // both of which run after the scan. 64*10112 = 647168 floats exactly fits.
    float* dT = out + (650000 - 64 * TSTRIDE);

    // hot engines bump 32-bit address words without carry: require the touched
    // windows not to cross a 4GiB boundary (deterministic per capture).
    ull ta = (ull)dT, pa = (ull)packed;
    int fast = ((ta & 0xFFFFFFFFull) + 0x280000ull <= 0x100000000ull) &&
               ((pa & 0xFFFFFFFFull) + 0x30000ull  <= 0x100000000ull) &&
               (ws_size >= need_bytes);

    assign_kernel<<<(E_NO + I_NO + 255) / 256, 256, 0, stream>>>(C_syn_e, C_syn_i, ae, ai);
    drive_kernel<<<T_DATA, 256, 0, stream>>>(S_e, S_i, w_raw, ae, ai, drive);
    transpose_kernel<<<158, 256, 0, stream>>>(drive, dT);   // covers t 0..10111
    scan_kernel<<<1, 64, 0, stream>>>(drive, dT, C_den, dec_raw, thr_raw, prop_raw, packed, fast);
    expand_kernel<<<T_DATA * SUB_NO / 256, 256, 0, stream>>>(packed, out + T_DATA);
    conv_kernel<<<(T_DATA + 255) / 256, 256, 0, stream>>>(packed, out);
}